// Round 20
// baseline (456.977 us; speedup 1.0000x reference)
//
#include <hip/hip_runtime.h>

#define NN 1024
#define TT 256
#define MAXDEG 96

typedef unsigned short u16;
typedef unsigned long long ull;

// LDS x layout (words, rank-indexed), per buffer xb[b][3104]:
//   [0..1023]    copy A: rank v at word v                      (bank v&31)
//   [1024..2047] copy B: 1024 + ((v&~31)|((v&31)^h)),          h=(v>>5)&31
//   [2048..3071] copy C: 2048 + ((v&~31)|((v&31)^((13h+5)&31)))
//   [3072..3103] zero sentinels (one per bank)
// Proven-bad variants (do not revisit): 4-copy/37KB LDS (R16, sim 313->490);
// 2-step STEP-macro unroll (R8/R18, sim ~330->~492 at equal VALU work);
// seq-pairing float2/b64 (R10, instruction count unchanged, conflicts worse).

__device__ __forceinline__ int bofsB(int v) {
    int h = (v >> 5) & 31;
    return 1024 + ((v & ~31) | ((v & 31) ^ h));
}
__device__ __forceinline__ int bofsC(int v) {
    int h = (v >> 5) & 31;
    return 2048 + ((v & ~31) | ((v & 31) ^ ((13 * h + 5) & 31)));
}
__device__ __forceinline__ int cnt_res(int pd, int res) {
    return (pd > res) ? (((pd - 1 - res) >> 5) + 1) : 0;
}
// TIGHT padding: slack 0..7 (avg 3.5) — relies on 3-choice+eviction matcher.
// (R6's tight-pad failure was with a 1-choice matcher; R17+ has eviction.)
__device__ __forceinline__ int pd_of(int deg) {
    int cap = deg < MAXDEG ? deg : MAXDEG;
    int pd = (cap + 7) & ~7;
    if (pd < 16) pd = 16;
    if (pd > MAXDEG) pd = MAXDEG;
    return pd;
}

// ---- K1: per-chunk nonzero counts of each adj column (wide: 256 blocks) ----
__global__ __launch_bounds__(64) void k1_count(const float* __restrict__ adj,
                                               int* __restrict__ cnt_part)
{
    int tid = blockIdx.x * 64 + threadIdx.x;
    int chunk = tid >> 10;
    int n = tid & 1023;
    int c = 0;
    for (int j = 0; j < 64; ++j)
        c += (adj[(chunk * 64 + j) * NN + n] != 0.0f) ? 1 : 0;
    cnt_part[chunk * NN + n] = c;
}

// ---- K23: fused totals + stable descending-pdeg rank (single block, LDS) ----
__global__ __launch_bounds__(1024) void k23_rank(const int* __restrict__ cnt_part,
                                                 int* __restrict__ deg,
                                                 int* __restrict__ rank_of,
                                                 int* __restrict__ node_of)
{
    __shared__ int pd_s[NN];
    const int n = threadIdx.x;
    int tot = 0;
    for (int c = 0; c < 16; ++c) tot += cnt_part[c * NN + n];
    deg[n] = tot;
    int my = pd_of(tot);
    pd_s[n] = my;
    __syncthreads();
    int r = 0;
    for (int m = 0; m < NN; ++m) {
        int pm = pd_s[m];                 // broadcast LDS read (conflict-free)
        r += (pm > my) || (pm == my && m < n);
    }
    rank_of[n] = r;
    node_of[r] = n;
}

// ---- K4: fill compact neighbor lists (wide: 256 blocks, coalesced) ----
__global__ __launch_bounds__(64) void k4_fill(const float* __restrict__ adj,
                                              const int* __restrict__ cnt_part,
                                              u16* __restrict__ nbrC)
{
    int tid = blockIdx.x * 64 + threadIdx.x;
    int chunk = tid >> 10;
    int n = tid & 1023;
    int pos = 0;
    for (int c = 0; c < chunk; ++c) pos += cnt_part[c * NN + n];
    for (int j = 0; j < 64; ++j) {
        int m = chunk * 64 + j;
        if (adj[m * NN + n] != 0.0f) {
            if (pos < MAXDEG) nbrC[n * MAXDEG + pos] = (u16)m;
            ++pos;
        }
    }
}

// ---- P3: least-loaded 3-choice greedy + BOUNDED depth-1 eviction (rank-ordered) ----
__device__ __forceinline__ int reloc_one(ull& freep, int pd, int l, int r, int tl,
                                         int vo, u16 (*who_s)[64],
                                         u16* __restrict__ nbr8, int& maxk)
{
    int ob0 = vo & 31, oh = (vo >> 5) & 31;
    int r0 = (ob0 - l) & 31;
    int r1 = ((ob0 ^ oh) - l) & 31;
    int r2 = ((ob0 ^ ((13 * oh + 5) & 31)) - l) & 31;
    int f0 = (int)((freep >> (2 * r0)) & 3);
    int f1 = (int)((freep >> (2 * r1)) & 3);
    int f2 = (int)((freep >> (2 * r2)) & 3);
    int ro, fo, ow;
    if (f0 > 0)      { ro = r0; fo = f0; ow = vo; }
    else if (f1 > 0) { ro = r1; fo = f1; ow = bofsB(vo); }
    else if (f2 > 0) { ro = r2; fo = f2; ow = bofsC(vo); }
    else return 0;
    int k2 = ro + 32 * (cnt_res(pd, ro) - fo);
    freep -= 1ull << (2 * ro);
    nbr8[((k2 >> 3) << 13) + (r << 3) + (k2 & 7)] = (u16)(ow * 4);
    who_s[k2][tl] = (u16)vo;
    if (k2 > maxk) maxk = k2;
    return 1;
}

__global__ __launch_bounds__(64) void p3_sched(const u16* __restrict__ nbrC,
                                               const int* __restrict__ deg,
                                               const int* __restrict__ rank_of,
                                               const int* __restrict__ node_of,
                                               u16* __restrict__ nbr8,
                                               int* __restrict__ ngrp_r,
                                               float* __restrict__ invd_r)
{
    __shared__ u16 who_s[MAXDEG][64];
    const int tl = threadIdx.x;
    const int r  = blockIdx.x * 64 + tl;   // rank this thread schedules
    const int n  = node_of[r];             // its node
    const int l  = tl;                     // r & 63 == tl
    const int dg = deg[n];
    const int cap = dg < MAXDEG ? dg : MAXDEG;
    const int pd = pd_of(dg);

    ull freep = 0;
    for (int res = 0; res < 32; ++res)
        freep |= (ull)cnt_res(pd, res) << (2 * res);
    for (int k = 0; k < pd; ++k) who_s[k][tl] = 0xFFFF;

    // sentinel-prefill all pd slots, one 16B store per group of 8
    for (int g = 0; g < (pd >> 3); ++g) {
        uint4 pk;
        unsigned w0 = (unsigned)((3072 + ((l + g * 8 + 0) & 31)) * 4);
        unsigned w1 = (unsigned)((3072 + ((l + g * 8 + 1) & 31)) * 4);
        unsigned w2 = (unsigned)((3072 + ((l + g * 8 + 2) & 31)) * 4);
        unsigned w3 = (unsigned)((3072 + ((l + g * 8 + 3) & 31)) * 4);
        unsigned w4 = (unsigned)((3072 + ((l + g * 8 + 4) & 31)) * 4);
        unsigned w5 = (unsigned)((3072 + ((l + g * 8 + 5) & 31)) * 4);
        unsigned w6 = (unsigned)((3072 + ((l + g * 8 + 6) & 31)) * 4);
        unsigned w7 = (unsigned)((3072 + ((l + g * 8 + 7) & 31)) * 4);
        pk.x = w0 | (w1 << 16);
        pk.y = w2 | (w3 << 16);
        pk.z = w4 | (w5 << 16);
        pk.w = w6 | (w7 << 16);
        *(uint4*)(nbr8 + (g << 13) + (r << 3)) = pk;
    }

    const uint4* __restrict__ row = (const uint4*)(nbrC + n * MAXDEG);
    int maxk = 15;

#define EMIT(K, WORD) nbr8[(((K) >> 3) << 13) + (r << 3) + ((K) & 7)] = (u16)((WORD) * 4)

    for (int c8 = 0; c8 < (cap + 7) / 8; ++c8) {
        uint4 w = row[c8];
        int id0 = w.x & 0xFFFF, id1 = w.x >> 16, id2 = w.y & 0xFFFF, id3 = w.y >> 16;
        int id4 = w.z & 0xFFFF, id5 = w.z >> 16, id6 = w.w & 0xFFFF, id7 = w.w >> 16;
        int rk[8];
        rk[0] = rank_of[id0]; rk[1] = rank_of[id1];
        rk[2] = rank_of[id2]; rk[3] = rank_of[id3];
        rk[4] = rank_of[id4]; rk[5] = rank_of[id5];
        rk[6] = rank_of[id6]; rk[7] = rank_of[id7];

        int lim = cap - c8 * 8; if (lim > 8) lim = 8;
        #pragma unroll
        for (int u = 0; u < 8; ++u) {
            if (u >= lim) break;
            int v = rk[u];
            int b0 = v & 31;
            int h  = (v >> 5) & 31;
            int res0 = (b0 - l) & 31;
            int res1 = ((b0 ^ h) - l) & 31;
            int res2 = ((b0 ^ ((13 * h + 5) & 31)) - l) & 31;
            int f0 = (int)((freep >> (2 * res0)) & 3);
            int f1 = (int)((freep >> (2 * res1)) & 3);
            int f2 = (int)((freep >> (2 * res2)) & 3);
            int resw, fw, word;
            if (f0 > 0 && f0 >= f1 && f0 >= f2) {
                resw = res0; fw = f0; word = v;
            } else if (f1 > 0 && f1 >= f2) {
                resw = res1; fw = f1; word = bofsB(v);
            } else if (f2 > 0) {
                resw = res2; fw = f2; word = bofsC(v);
            } else {
                fw = 0; resw = 0; word = v;
            }
            if (fw > 0) {
                int kslot = resw + 32 * (cnt_res(pd, resw) - fw);
                freep -= 1ull << (2 * resw);
                EMIT(kslot, word);
                who_s[kslot][tl] = (u16)v;
                if (kslot > maxk) maxk = kslot;
            } else {
                int done = 0;
                if (cnt_res(pd, res0) > 0) {
                    int vo = who_s[res0][tl];
                    if (vo != 0xFFFF &&
                        reloc_one(freep, pd, l, r, tl, vo, who_s, nbr8, maxk)) {
                        EMIT(res0, v);
                        who_s[res0][tl] = (u16)v;
                        if (res0 > maxk) maxk = res0;
                        done = 1;
                    }
                }
                if (!done && cnt_res(pd, res1) > 0) {
                    int vo = who_s[res1][tl];
                    if (vo != 0xFFFF &&
                        reloc_one(freep, pd, l, r, tl, vo, who_s, nbr8, maxk)) {
                        EMIT(res1, bofsB(v));
                        who_s[res1][tl] = (u16)v;
                        if (res1 > maxk) maxk = res1;
                        done = 1;
                    }
                }
                if (!done && cnt_res(pd, res2) > 0) {
                    int vo = who_s[res2][tl];
                    if (vo != 0xFFFF &&
                        reloc_one(freep, pd, l, r, tl, vo, who_s, nbr8, maxk)) {
                        EMIT(res2, bofsC(v));
                        who_s[res2][tl] = (u16)v;
                        if (res2 > maxk) maxk = res2;
                        done = 1;
                    }
                }
                if (!done) {
                    for (int res = 0; res < 32; ++res) {
                        int f = (int)((freep >> (2 * res)) & 3);
                        if (f > 0) {
                            int kslot = res + 32 * (cnt_res(pd, res) - f);
                            freep -= 1ull << (2 * res);
                            EMIT(kslot, v);
                            who_s[kslot][tl] = (u16)v;
                            if (kslot > maxk) maxk = kslot;
                            break;
                        }
                    }
                }
            }
        }
    }
#undef EMIT
    ngrp_r[r] = (maxk >> 3) + 1;
    invd_r[r] = 0.35f / ((float)dg + 1e-7f);   // OMEGA*GAMMA/(in_deg+1e-7)
}

// LDS-only barrier: order LDS ops, do NOT drain vmcnt.
#define LDS_BARRIER() asm volatile("s_waitcnt lgkmcnt(0)\n\ts_barrier" ::: "memory")

// ---------------- main simulation (R17 structure, verbatim — rolled loop) ----------------
__global__ __launch_bounds__(1024) void sim_kernel(
    const float* __restrict__ x0, const float* __restrict__ t,
    const float* __restrict__ speed, const float* __restrict__ vola,
    const float* __restrict__ noise, const int* __restrict__ items,
    const u16* __restrict__ nbr8, const int* __restrict__ node_of,
    const int* __restrict__ rank_of,
    const int* __restrict__ ngrp_r, const float* __restrict__ invd_r,
    float* __restrict__ out)
{
    __shared__ float xb[2][3104];       // A + B + C copies + 32 zero sentinels
    __shared__ float4 cst[TT - 1];      // per-step {e, scale, item_as_float, -}

    const int s   = blockIdx.x;
    const int tid = threadIdx.x;

    const float sp = speed[s];
    const float vo = vola[s];

    if (tid < TT - 1) {
        float t0 = t[s * TT + tid], t1 = t[s * TT + tid + 1];
        float dt = t1 - t0;
        float e  = expf(-sp * dt);
        float sc = vo * sqrtf((1.0f - e * e) / (2.0f * sp + 1e-6f));
        int   it = items[s * TT + tid + 1];
        cst[tid] = make_float4(e, sc, __int_as_float(it), 0.0f);
    }

    const int   m     = node_of[tid];     // node this thread simulates
    const int   r_out = rank_of[tid];     // rank holding node `tid` (for out staging)
    const int   wB    = bofsB(tid);       // this thread's copy-B/C write words
    const int   wC    = bofsC(tid);

    const float x0m = x0[m];
    xb[0][tid] = x0m;
    xb[0][wB]  = x0m;
    xb[0][wC]  = x0m;
    if (tid < 32) { xb[0][3072 + tid] = 0.0f; xb[1][3072 + tid] = 0.0f; }

    float* __restrict__ outp = out + (size_t)s * TT * NN + tid;
    outp[0] = x0[tid];                    // coalesced

    const int   ng   = ngrp_r[tid];
    const float invd = invd_r[tid];
    const int   item0 = items[s * TT];
    float a_f = (m == item0) ? 1.0f : 0.0f;
    float s_f = 0.0f;

    // per-node noise register pipeline, 2 steps ahead
    const float* __restrict__ nzm = noise + (size_t)s * (TT - 1) * NN + m;
    float nzA = nzm[0];
    float nzB = nzm[NN];

    // preload ALL neighbor index groups into registers
    const uint4* __restrict__ nb = (const uint4*)nbr8 + tid;   // group stride 1024
    uint4 q0  = nb[0];
    uint4 q1  = nb[1024];
    uint4 q2  = nb[2048];
    uint4 q3  = nb[3072];
    uint4 q4  = nb[4096];
    uint4 q5  = nb[5120];
    uint4 q6  = nb[6144];
    uint4 q7  = nb[7168];
    uint4 q8  = nb[8192];
    uint4 q9  = nb[9216];
    uint4 q10 = nb[10240];
    uint4 q11 = nb[11264];

    __syncthreads();                      // one full barrier after init

    float x_own = x0m;

#define G8(V)                                                   \
    acc += *(const float*)(xc + ((V).x & 0xFFFFu));             \
    acc += *(const float*)(xc + ((V).x >> 16));                 \
    acc += *(const float*)(xc + ((V).y & 0xFFFFu));             \
    acc += *(const float*)(xc + ((V).y >> 16));                 \
    acc += *(const float*)(xc + ((V).z & 0xFFFFu));             \
    acc += *(const float*)(xc + ((V).z >> 16));                 \
    acc += *(const float*)(xc + ((V).w & 0xFFFFu));             \
    acc += *(const float*)(xc + ((V).w >> 16));

    for (int i = 0; i < TT - 1; ++i) {
        const float* __restrict__ src = xb[i & 1];
        float* __restrict__ dst       = xb[(i + 1) & 1];
        const float4 c = cst[i];

        // prefetch noise for step i+2 (latency hidden across 2 barriers)
        int ipre = (i + 2 < TT - 1) ? (i + 2) : (TT - 2);
        float nz_new = nzm[(size_t)ipre * NN];

        float xi_lin = src[r_out];        // prev value of node `tid` (permutation read)

        float acc = 0.0f;
        const char* xc = (const char*)src;
        G8(q0); G8(q1);
        if (ng > 2) { G8(q2);
        if (ng > 3) { G8(q3);
        if (ng > 4) { G8(q4);
        if (ng > 5) { G8(q5);
        if (ng > 6) { G8(q6);
        if (ng > 7) { G8(q7);
        if (ng > 8) { G8(q8);
        if (ng > 9) { G8(q9);
        if (ng > 10){ G8(q10);
        if (ng > 11){ G8(q11); } } } } } } } } } }

        float nz = nzA * c.y;
        float r  = s_f / (a_f + 1e-6f);
        float level = fmaf(acc, invd, 0.5f * r * r);
        float xn = fmaf(x_own, c.x, fmaf(1.0f - c.x, level, nz));

        dst[tid] = xn;                    // copy A: linear, conflict-free
        dst[wB]  = xn;                    // copy B: XOR-permuted, conflict-free
        dst[wC]  = xn;                    // copy C: XOR-permuted, conflict-free
        if (i) outp[(size_t)i * NN] = xi_lin;          // coalesced, 1-step delayed

        if (m == __float_as_int(c.z)) {
            a_f += 1.0f;
            s_f += (xn >= 0.0f) ? 1.0f : 0.0f;
        }
        x_own = xn;
        nzA = nzB; nzB = nz_new;
        LDS_BARRIER();                    // LDS-only: no vmcnt drain
    }
#undef G8

    outp[(size_t)(TT - 1) * NN] = xb[1][r_out];   // final state lives in buffer 1
}

extern "C" void kernel_launch(void* const* d_in, const int* in_sizes, int n_in,
                              void* d_out, int out_size, void* d_ws, size_t ws_size,
                              hipStream_t stream)
{
    const float* x0    = (const float*)d_in[0];
    const float* t     = (const float*)d_in[1];
    const float* speed = (const float*)d_in[2];
    const float* vola  = (const float*)d_in[3];
    const float* adj   = (const float*)d_in[4];
    const float* noise = (const float*)d_in[5];
    const int*   items = (const int*)d_in[6];
    float* out = (float*)d_out;

    char* ws = (char*)d_ws;
    int*   cnt_part = (int*)ws;                       // 64 KB
    int*   deg      = (int*)(ws + 65536);             // 4 KB
    int*   rank_of  = (int*)(ws + 65536 + 4096);      // 4 KB
    int*   node_of  = (int*)(ws + 65536 + 8192);      // 4 KB
    int*   ngrp_r   = (int*)(ws + 65536 + 12288);     // 4 KB
    float* invd_r   = (float*)(ws + 65536 + 16384);   // 4 KB
    u16*   nbrC     = (u16*)(ws + 65536 + 20480);     // 192 KB
    u16*   nbr8     = (u16*)(ws + 65536 + 20480 + 196608); // 192 KB

    k1_count<<<256, 64, 0, stream>>>(adj, cnt_part);
    k23_rank<<<1, 1024, 0, stream>>>(cnt_part, deg, rank_of, node_of);
    k4_fill<<<256, 64, 0, stream>>>(adj, cnt_part, nbrC);
    p3_sched<<<16, 64, 0, stream>>>(nbrC, deg, rank_of, node_of, nbr8, ngrp_r, invd_r);
    sim_kernel<<<64, 1024, 0, stream>>>(x0, t, speed, vola, noise, items,
                                        nbr8, node_of, rank_of, ngrp_r, invd_r, out);
}

// Round 21
// 410.088 us; speedup vs baseline: 1.1143x; 1.1143x over previous
//
#include <hip/hip_runtime.h>

#define NN 1024
#define TT 256
#define MAXDEG 96

typedef unsigned short u16;
typedef unsigned long long ull;

// LDS x layout (words, rank-indexed), per buffer xb[b][3104]:
//   [0..1023]    copy A: rank v at word v                      (bank v&31)
//   [1024..2047] copy B: 1024 + ((v&~31)|((v&31)^h)),          h=(v>>5)&31
//   [2048..3071] copy C: 2048 + ((v&~31)|((v&31)^((13h+5)&31)))
//   [3072..3103] zero sentinels (one per bank)
// Proven-bad variants (do not revisit): 4-copy/37KB LDS (R16, sim 313->490);
// 2-step STEP-macro unroll (R8/R18, sim ~330->~492 at equal VALU work);
// seq-pairing float2/b64 (R10); tight pd=(cap+7)&~7 (R20, conflicts 2.7e6->13.4e6).

__device__ __forceinline__ int bofsB(int v) {
    int h = (v >> 5) & 31;
    return 1024 + ((v & ~31) | ((v & 31) ^ h));
}
__device__ __forceinline__ int bofsC(int v) {
    int h = (v >> 5) & 31;
    return 2048 + ((v & ~31) | ((v & 31) ^ ((13 * h + 5) & 31)));
}
__device__ __forceinline__ int cnt_res(int pd, int res) {
    return (pd > res) ? (((pd - 1 - res) >> 5) + 1) : 0;
}
__device__ __forceinline__ int pd_of(int deg) {
    int cap = deg < MAXDEG ? deg : MAXDEG;
    int pd = (cap + 15) & ~7;
    if (pd < 16) pd = 16;
    if (pd > MAXDEG) pd = MAXDEG;
    return pd;
}

// ---- K1: per-chunk nonzero counts of each adj column (wide: 256 blocks) ----
__global__ __launch_bounds__(64) void k1_count(const float* __restrict__ adj,
                                               int* __restrict__ cnt_part)
{
    int tid = blockIdx.x * 64 + threadIdx.x;
    int chunk = tid >> 10;
    int n = tid & 1023;
    int c = 0;
    for (int j = 0; j < 64; ++j)
        c += (adj[(chunk * 64 + j) * NN + n] != 0.0f) ? 1 : 0;
    cnt_part[chunk * NN + n] = c;
}

// ---- K23: fused totals + stable descending-pdeg rank (single block, LDS) ----
// Emits deg_r (degree by RANK) so p3 needs no node_of/deg lookups.
__global__ __launch_bounds__(1024) void k23_rank(const int* __restrict__ cnt_part,
                                                 int* __restrict__ deg_r,
                                                 int* __restrict__ rank_of,
                                                 int* __restrict__ node_of)
{
    __shared__ int pd_s[NN];
    const int n = threadIdx.x;
    int tot = 0;
    for (int c = 0; c < 16; ++c) tot += cnt_part[c * NN + n];
    int my = pd_of(tot);
    pd_s[n] = my;
    __syncthreads();
    int r = 0;
    for (int m = 0; m < NN; ++m) {
        int pm = pd_s[m];                 // broadcast LDS read (conflict-free)
        r += (pm > my) || (pm == my && m < n);
    }
    rank_of[n] = r;
    node_of[r] = n;
    deg_r[r]   = tot;
}

// ---- K4: fill compact neighbor lists storing neighbor RANKS directly ----
// All 64 threads of a block share one row-chunk -> stage rank_of[chunk] in LDS
// once; per-row rank read is a broadcast (free). Removes p3's per-neighbor gather.
__global__ __launch_bounds__(64) void k4_fill(const float* __restrict__ adj,
                                              const int* __restrict__ cnt_part,
                                              const int* __restrict__ rank_of,
                                              u16* __restrict__ nbrR)
{
    __shared__ u16 rnk_s[64];
    int tid = blockIdx.x * 64 + threadIdx.x;
    int chunk = tid >> 10;
    int n = tid & 1023;
    rnk_s[threadIdx.x] = (u16)rank_of[chunk * 64 + threadIdx.x];
    __syncthreads();
    int pos = 0;
    for (int c = 0; c < chunk; ++c) pos += cnt_part[c * NN + n];
    for (int j = 0; j < 64; ++j) {
        int m = chunk * 64 + j;
        if (adj[m * NN + n] != 0.0f) {
            if (pos < MAXDEG) nbrR[n * MAXDEG + pos] = rnk_s[j];
            ++pos;
        }
    }
}

// ---- P3: least-loaded 3-choice greedy + BOUNDED depth-1 eviction ----
// RANK-ordered AND gather-free: nbrR already holds ranks; deg via deg_r[r].
__device__ __forceinline__ int reloc_one(ull& freep, int pd, int l, int r, int tl,
                                         int vo, u16 (*who_s)[64],
                                         u16* __restrict__ nbr8, int& maxk)
{
    int ob0 = vo & 31, oh = (vo >> 5) & 31;
    int r0 = (ob0 - l) & 31;
    int r1 = ((ob0 ^ oh) - l) & 31;
    int r2 = ((ob0 ^ ((13 * oh + 5) & 31)) - l) & 31;
    int f0 = (int)((freep >> (2 * r0)) & 3);
    int f1 = (int)((freep >> (2 * r1)) & 3);
    int f2 = (int)((freep >> (2 * r2)) & 3);
    int ro, fo, ow;
    if (f0 > 0)      { ro = r0; fo = f0; ow = vo; }
    else if (f1 > 0) { ro = r1; fo = f1; ow = bofsB(vo); }
    else if (f2 > 0) { ro = r2; fo = f2; ow = bofsC(vo); }
    else return 0;
    int k2 = ro + 32 * (cnt_res(pd, ro) - fo);
    freep -= 1ull << (2 * ro);
    nbr8[((k2 >> 3) << 13) + (r << 3) + (k2 & 7)] = (u16)(ow * 4);
    who_s[k2][tl] = (u16)vo;
    if (k2 > maxk) maxk = k2;
    return 1;
}

__global__ __launch_bounds__(64) void p3_sched(const u16* __restrict__ nbrR,
                                               const int* __restrict__ deg_r,
                                               const int* __restrict__ node_of,
                                               u16* __restrict__ nbr8,
                                               int* __restrict__ ngrp_r,
                                               float* __restrict__ invd_r)
{
    __shared__ u16 who_s[MAXDEG][64];
    const int tl = threadIdx.x;
    const int r  = blockIdx.x * 64 + tl;   // rank this thread schedules
    const int l  = tl;                     // r & 63 == tl
    const int dg = deg_r[r];
    const int n  = node_of[r];             // its node (for nbrR row)
    const int cap = dg < MAXDEG ? dg : MAXDEG;
    const int pd = pd_of(dg);

    ull freep = 0;
    for (int res = 0; res < 32; ++res)
        freep |= (ull)cnt_res(pd, res) << (2 * res);
    for (int k = 0; k < pd; ++k) who_s[k][tl] = 0xFFFF;

    // sentinel-prefill all pd slots, one 16B store per group of 8
    for (int g = 0; g < (pd >> 3); ++g) {
        uint4 pk;
        unsigned w0 = (unsigned)((3072 + ((l + g * 8 + 0) & 31)) * 4);
        unsigned w1 = (unsigned)((3072 + ((l + g * 8 + 1) & 31)) * 4);
        unsigned w2 = (unsigned)((3072 + ((l + g * 8 + 2) & 31)) * 4);
        unsigned w3 = (unsigned)((3072 + ((l + g * 8 + 3) & 31)) * 4);
        unsigned w4 = (unsigned)((3072 + ((l + g * 8 + 4) & 31)) * 4);
        unsigned w5 = (unsigned)((3072 + ((l + g * 8 + 5) & 31)) * 4);
        unsigned w6 = (unsigned)((3072 + ((l + g * 8 + 6) & 31)) * 4);
        unsigned w7 = (unsigned)((3072 + ((l + g * 8 + 7) & 31)) * 4);
        pk.x = w0 | (w1 << 16);
        pk.y = w2 | (w3 << 16);
        pk.z = w4 | (w5 << 16);
        pk.w = w6 | (w7 << 16);
        *(uint4*)(nbr8 + (g << 13) + (r << 3)) = pk;
    }

    const uint4* __restrict__ row = (const uint4*)(nbrR + n * MAXDEG);
    int maxk = 15;

#define EMIT(K, WORD) nbr8[(((K) >> 3) << 13) + (r << 3) + ((K) & 7)] = (u16)((WORD) * 4)

    for (int c8 = 0; c8 < (cap + 7) / 8; ++c8) {
        uint4 w = row[c8];
        int rk[8];
        rk[0] = w.x & 0xFFFF; rk[1] = w.x >> 16;
        rk[2] = w.y & 0xFFFF; rk[3] = w.y >> 16;
        rk[4] = w.z & 0xFFFF; rk[5] = w.z >> 16;
        rk[6] = w.w & 0xFFFF; rk[7] = w.w >> 16;

        int lim = cap - c8 * 8; if (lim > 8) lim = 8;
        #pragma unroll
        for (int u = 0; u < 8; ++u) {
            if (u >= lim) break;
            int v = rk[u];
            int b0 = v & 31;
            int h  = (v >> 5) & 31;
            int res0 = (b0 - l) & 31;
            int res1 = ((b0 ^ h) - l) & 31;
            int res2 = ((b0 ^ ((13 * h + 5) & 31)) - l) & 31;
            int f0 = (int)((freep >> (2 * res0)) & 3);
            int f1 = (int)((freep >> (2 * res1)) & 3);
            int f2 = (int)((freep >> (2 * res2)) & 3);
            int resw, fw, word;
            if (f0 > 0 && f0 >= f1 && f0 >= f2) {
                resw = res0; fw = f0; word = v;
            } else if (f1 > 0 && f1 >= f2) {
                resw = res1; fw = f1; word = bofsB(v);
            } else if (f2 > 0) {
                resw = res2; fw = f2; word = bofsC(v);
            } else {
                fw = 0; resw = 0; word = v;
            }
            if (fw > 0) {
                int kslot = resw + 32 * (cnt_res(pd, resw) - fw);
                freep -= 1ull << (2 * resw);
                EMIT(kslot, word);
                who_s[kslot][tl] = (u16)v;
                if (kslot > maxk) maxk = kslot;
            } else {
                int done = 0;
                if (cnt_res(pd, res0) > 0) {
                    int vo = who_s[res0][tl];
                    if (vo != 0xFFFF &&
                        reloc_one(freep, pd, l, r, tl, vo, who_s, nbr8, maxk)) {
                        EMIT(res0, v);
                        who_s[res0][tl] = (u16)v;
                        if (res0 > maxk) maxk = res0;
                        done = 1;
                    }
                }
                if (!done && cnt_res(pd, res1) > 0) {
                    int vo = who_s[res1][tl];
                    if (vo != 0xFFFF &&
                        reloc_one(freep, pd, l, r, tl, vo, who_s, nbr8, maxk)) {
                        EMIT(res1, bofsB(v));
                        who_s[res1][tl] = (u16)v;
                        if (res1 > maxk) maxk = res1;
                        done = 1;
                    }
                }
                if (!done && cnt_res(pd, res2) > 0) {
                    int vo = who_s[res2][tl];
                    if (vo != 0xFFFF &&
                        reloc_one(freep, pd, l, r, tl, vo, who_s, nbr8, maxk)) {
                        EMIT(res2, bofsC(v));
                        who_s[res2][tl] = (u16)v;
                        if (res2 > maxk) maxk = res2;
                        done = 1;
                    }
                }
                if (!done) {
                    for (int res = 0; res < 32; ++res) {
                        int f = (int)((freep >> (2 * res)) & 3);
                        if (f > 0) {
                            int kslot = res + 32 * (cnt_res(pd, res) - f);
                            freep -= 1ull << (2 * res);
                            EMIT(kslot, v);
                            who_s[kslot][tl] = (u16)v;
                            if (kslot > maxk) maxk = kslot;
                            break;
                        }
                    }
                }
            }
        }
    }
#undef EMIT
    ngrp_r[r] = (maxk >> 3) + 1;
    invd_r[r] = 0.35f / ((float)dg + 1e-7f);   // OMEGA*GAMMA/(in_deg+1e-7)
}

// LDS-only barrier: order LDS ops, do NOT drain vmcnt.
#define LDS_BARRIER() asm volatile("s_waitcnt lgkmcnt(0)\n\ts_barrier" ::: "memory")

// ---------------- main simulation (R17/R19 structure, verbatim — rolled loop) ----------------
__global__ __launch_bounds__(1024) void sim_kernel(
    const float* __restrict__ x0, const float* __restrict__ t,
    const float* __restrict__ speed, const float* __restrict__ vola,
    const float* __restrict__ noise, const int* __restrict__ items,
    const u16* __restrict__ nbr8, const int* __restrict__ node_of,
    const int* __restrict__ rank_of,
    const int* __restrict__ ngrp_r, const float* __restrict__ invd_r,
    float* __restrict__ out)
{
    __shared__ float xb[2][3104];       // A + B + C copies + 32 zero sentinels
    __shared__ float4 cst[TT - 1];      // per-step {e, scale, item_as_float, -}

    const int s   = blockIdx.x;
    const int tid = threadIdx.x;

    const float sp = speed[s];
    const float vo = vola[s];

    if (tid < TT - 1) {
        float t0 = t[s * TT + tid], t1 = t[s * TT + tid + 1];
        float dt = t1 - t0;
        float e  = expf(-sp * dt);
        float sc = vo * sqrtf((1.0f - e * e) / (2.0f * sp + 1e-6f));
        int   it = items[s * TT + tid + 1];
        cst[tid] = make_float4(e, sc, __int_as_float(it), 0.0f);
    }

    const int   m     = node_of[tid];     // node this thread simulates
    const int   r_out = rank_of[tid];     // rank holding node `tid` (for out staging)
    const int   wB    = bofsB(tid);       // this thread's copy-B/C write words
    const int   wC    = bofsC(tid);

    const float x0m = x0[m];
    xb[0][tid] = x0m;
    xb[0][wB]  = x0m;
    xb[0][wC]  = x0m;
    if (tid < 32) { xb[0][3072 + tid] = 0.0f; xb[1][3072 + tid] = 0.0f; }

    float* __restrict__ outp = out + (size_t)s * TT * NN + tid;
    outp[0] = x0[tid];                    // coalesced

    const int   ng   = ngrp_r[tid];
    const float invd = invd_r[tid];
    const int   item0 = items[s * TT];
    float a_f = (m == item0) ? 1.0f : 0.0f;
    float s_f = 0.0f;

    // per-node noise register pipeline, 2 steps ahead
    const float* __restrict__ nzm = noise + (size_t)s * (TT - 1) * NN + m;
    float nzA = nzm[0];
    float nzB = nzm[NN];

    // preload ALL neighbor index groups into registers
    const uint4* __restrict__ nb = (const uint4*)nbr8 + tid;   // group stride 1024
    uint4 q0  = nb[0];
    uint4 q1  = nb[1024];
    uint4 q2  = nb[2048];
    uint4 q3  = nb[3072];
    uint4 q4  = nb[4096];
    uint4 q5  = nb[5120];
    uint4 q6  = nb[6144];
    uint4 q7  = nb[7168];
    uint4 q8  = nb[8192];
    uint4 q9  = nb[9216];
    uint4 q10 = nb[10240];
    uint4 q11 = nb[11264];

    __syncthreads();                      // one full barrier after init

    float x_own = x0m;

#define G8(V)                                                   \
    acc += *(const float*)(xc + ((V).x & 0xFFFFu));             \
    acc += *(const float*)(xc + ((V).x >> 16));                 \
    acc += *(const float*)(xc + ((V).y & 0xFFFFu));             \
    acc += *(const float*)(xc + ((V).y >> 16));                 \
    acc += *(const float*)(xc + ((V).z & 0xFFFFu));             \
    acc += *(const float*)(xc + ((V).z >> 16));                 \
    acc += *(const float*)(xc + ((V).w & 0xFFFFu));             \
    acc += *(const float*)(xc + ((V).w >> 16));

    for (int i = 0; i < TT - 1; ++i) {
        const float* __restrict__ src = xb[i & 1];
        float* __restrict__ dst       = xb[(i + 1) & 1];
        const float4 c = cst[i];

        // prefetch noise for step i+2 (latency hidden across 2 barriers)
        int ipre = (i + 2 < TT - 1) ? (i + 2) : (TT - 2);
        float nz_new = nzm[(size_t)ipre * NN];

        float xi_lin = src[r_out];        // prev value of node `tid` (permutation read)

        float acc = 0.0f;
        const char* xc = (const char*)src;
        G8(q0); G8(q1);
        if (ng > 2) { G8(q2);
        if (ng > 3) { G8(q3);
        if (ng > 4) { G8(q4);
        if (ng > 5) { G8(q5);
        if (ng > 6) { G8(q6);
        if (ng > 7) { G8(q7);
        if (ng > 8) { G8(q8);
        if (ng > 9) { G8(q9);
        if (ng > 10){ G8(q10);
        if (ng > 11){ G8(q11); } } } } } } } } } }

        float nz = nzA * c.y;
        float r  = s_f / (a_f + 1e-6f);
        float level = fmaf(acc, invd, 0.5f * r * r);
        float xn = fmaf(x_own, c.x, fmaf(1.0f - c.x, level, nz));

        dst[tid] = xn;                    // copy A: linear, conflict-free
        dst[wB]  = xn;                    // copy B: XOR-permuted, conflict-free
        dst[wC]  = xn;                    // copy C: XOR-permuted, conflict-free
        if (i) outp[(size_t)i * NN] = xi_lin;          // coalesced, 1-step delayed

        if (m == __float_as_int(c.z)) {
            a_f += 1.0f;
            s_f += (xn >= 0.0f) ? 1.0f : 0.0f;
        }
        x_own = xn;
        nzA = nzB; nzB = nz_new;
        LDS_BARRIER();                    // LDS-only: no vmcnt drain
    }
#undef G8

    outp[(size_t)(TT - 1) * NN] = xb[1][r_out];   // final state lives in buffer 1
}

extern "C" void kernel_launch(void* const* d_in, const int* in_sizes, int n_in,
                              void* d_out, int out_size, void* d_ws, size_t ws_size,
                              hipStream_t stream)
{
    const float* x0    = (const float*)d_in[0];
    const float* t     = (const float*)d_in[1];
    const float* speed = (const float*)d_in[2];
    const float* vola  = (const float*)d_in[3];
    const float* adj   = (const float*)d_in[4];
    const float* noise = (const float*)d_in[5];
    const int*   items = (const int*)d_in[6];
    float* out = (float*)d_out;

    char* ws = (char*)d_ws;
    int*   cnt_part = (int*)ws;                       // 64 KB
    int*   deg_r    = (int*)(ws + 65536);             // 4 KB (degree by rank)
    int*   rank_of  = (int*)(ws + 65536 + 4096);      // 4 KB
    int*   node_of  = (int*)(ws + 65536 + 8192);      // 4 KB
    int*   ngrp_r   = (int*)(ws + 65536 + 12288);     // 4 KB
    float* invd_r   = (float*)(ws + 65536 + 16384);   // 4 KB
    u16*   nbrR     = (u16*)(ws + 65536 + 20480);     // 192 KB (neighbor RANKS)
    u16*   nbr8     = (u16*)(ws + 65536 + 20480 + 196608); // 192 KB

    k1_count<<<256, 64, 0, stream>>>(adj, cnt_part);
    k23_rank<<<1, 1024, 0, stream>>>(cnt_part, deg_r, rank_of, node_of);
    k4_fill<<<256, 64, 0, stream>>>(adj, cnt_part, rank_of, nbrR);
    p3_sched<<<16, 64, 0, stream>>>(nbrR, deg_r, node_of, nbr8, ngrp_r, invd_r);
    sim_kernel<<<64, 1024, 0, stream>>>(x0, t, speed, vola, noise, items,
                                        nbr8, node_of, rank_of, ngrp_r, invd_r, out);
}

// Round 22
// 409.954 us; speedup vs baseline: 1.1147x; 1.0003x over previous
//
#include <hip/hip_runtime.h>

#define NN 1024
#define TT 256
#define MAXDEG 96

typedef unsigned short u16;
typedef unsigned long long ull;

// LDS x layout (words, rank-indexed), per buffer xb[b][3104]:
//   [0..1023]    copy A: rank v at word v                      (bank v&31)
//   [1024..2047] copy B: 1024 + ((v&~31)|((v&31)^h)),          h=(v>>5)&31
//   [2048..3071] copy C: 2048 + ((v&~31)|((v&31)^((13h+5)&31)))
//   [3072..3103] zero sentinels (one per bank)
// Proven-bad variants (do not revisit): 4-copy/37KB LDS (R16, sim 313->490);
// 2-step STEP-macro unroll (R8/R18, sim ~330->~492 at equal VALU work);
// seq-pairing float2/b64 (R10); tight pd=(cap+7)&~7 (R20, conflicts 2.7e6->13.4e6).

__device__ __forceinline__ int bofsB(int v) {
    int h = (v >> 5) & 31;
    return 1024 + ((v & ~31) | ((v & 31) ^ h));
}
__device__ __forceinline__ int bofsC(int v) {
    int h = (v >> 5) & 31;
    return 2048 + ((v & ~31) | ((v & 31) ^ ((13 * h + 5) & 31)));
}
// decode occupant rank from stored word (perms preserve bits 5..9 = h)
__device__ __forceinline__ int v_of_word(int w) {
    if (w < 1024) return w;
    int base = w & 1023;
    int h = (base >> 5) & 31;
    if (w < 2048) return (base & ~31) | ((base & 31) ^ h);
    return (base & ~31) | ((base & 31) ^ ((13 * h + 5) & 31));
}
__device__ __forceinline__ int cnt_res(int pd, int res) {
    return (pd > res) ? (((pd - 1 - res) >> 5) + 1) : 0;
}
__device__ __forceinline__ int pd_of(int deg) {
    int cap = deg < MAXDEG ? deg : MAXDEG;
    int pd = (cap + 15) & ~7;
    if (pd < 16) pd = 16;
    if (pd > MAXDEG) pd = MAXDEG;
    return pd;
}

// ---- K1: per-chunk nonzero counts of each adj column (wide: 256 blocks) ----
__global__ __launch_bounds__(64) void k1_count(const float* __restrict__ adj,
                                               int* __restrict__ cnt_part)
{
    int tid = blockIdx.x * 64 + threadIdx.x;
    int chunk = tid >> 10;
    int n = tid & 1023;
    int c = 0;
    for (int j = 0; j < 64; ++j)
        c += (adj[(chunk * 64 + j) * NN + n] != 0.0f) ? 1 : 0;
    cnt_part[chunk * NN + n] = c;
}

// ---- K23: fused totals + stable descending-pdeg rank (single block, LDS) ----
__global__ __launch_bounds__(1024) void k23_rank(const int* __restrict__ cnt_part,
                                                 int* __restrict__ deg_r,
                                                 int* __restrict__ rank_of,
                                                 int* __restrict__ node_of)
{
    __shared__ int pd_s[NN];
    const int n = threadIdx.x;
    int tot = 0;
    for (int c = 0; c < 16; ++c) tot += cnt_part[c * NN + n];
    int my = pd_of(tot);
    pd_s[n] = my;
    __syncthreads();
    int r = 0;
    for (int m = 0; m < NN; ++m) {
        int pm = pd_s[m];                 // broadcast LDS read (conflict-free)
        r += (pm > my) || (pm == my && m < n);
    }
    rank_of[n] = r;
    node_of[r] = n;
    deg_r[r]   = tot;
}

// ---- K4: fill compact neighbor lists storing neighbor RANKS directly ----
__global__ __launch_bounds__(64) void k4_fill(const float* __restrict__ adj,
                                              const int* __restrict__ cnt_part,
                                              const int* __restrict__ rank_of,
                                              u16* __restrict__ nbrR)
{
    __shared__ u16 rnk_s[64];
    int tid = blockIdx.x * 64 + threadIdx.x;
    int chunk = tid >> 10;
    int n = tid & 1023;
    rnk_s[threadIdx.x] = (u16)rank_of[chunk * 64 + threadIdx.x];
    __syncthreads();
    int pos = 0;
    for (int c = 0; c < chunk; ++c) pos += cnt_part[c * NN + n];
    for (int j = 0; j < 64; ++j) {
        int m = chunk * 64 + j;
        if (adj[m * NN + n] != 0.0f) {
            if (pos < MAXDEG) nbrR[n * MAXDEG + pos] = rnk_s[j];
            ++pos;
        }
    }
}

// ---- P3: least-loaded 3-choice greedy + bounded depth-1 eviction ----
// LDS-resident slot table (word_s holds the stored WORD; occupant decodable via
// v_of_word). All placement writes hit LDS; final emit is <=12 uint4 global
// stores per thread instead of ~40 scattered u16 stores.
__device__ __forceinline__ int reloc_one(ull& freep, int pd, int l, int tl,
                                         int vo, u16 (*word_s)[64])
{
    int ob0 = vo & 31, oh = (vo >> 5) & 31;
    int r0 = (ob0 - l) & 31;
    int r1 = ((ob0 ^ oh) - l) & 31;
    int r2 = ((ob0 ^ ((13 * oh + 5) & 31)) - l) & 31;
    int f0 = (int)((freep >> (2 * r0)) & 3);
    int f1 = (int)((freep >> (2 * r1)) & 3);
    int f2 = (int)((freep >> (2 * r2)) & 3);
    int ro, fo, ow;
    if (f0 > 0)      { ro = r0; fo = f0; ow = vo; }
    else if (f1 > 0) { ro = r1; fo = f1; ow = bofsB(vo); }
    else if (f2 > 0) { ro = r2; fo = f2; ow = bofsC(vo); }
    else return -1;
    int k2 = ro + 32 * (cnt_res(pd, ro) - fo);
    freep -= 1ull << (2 * ro);
    word_s[k2][tl] = (u16)ow;
    return k2;
}

__global__ __launch_bounds__(64) void p3_sched(const u16* __restrict__ nbrR,
                                               const int* __restrict__ deg_r,
                                               const int* __restrict__ node_of,
                                               u16* __restrict__ nbr8,
                                               int* __restrict__ ngrp_r,
                                               float* __restrict__ invd_r)
{
    __shared__ u16 word_s[MAXDEG][64];     // slot -> word (lane-major, 2-way = free)
    const int tl = threadIdx.x;
    const int r  = blockIdx.x * 64 + tl;   // rank this thread schedules
    const int l  = tl;                     // r & 63 == tl
    const int dg = deg_r[r];
    const int n  = node_of[r];
    const int cap = dg < MAXDEG ? dg : MAXDEG;
    const int pd = pd_of(dg);

    ull freep = 0;
    for (int res = 0; res < 32; ++res)
        freep |= (ull)cnt_res(pd, res) << (2 * res);

    // sentinel-prefill in LDS (free slots have word >= 3072)
    for (int k = 0; k < pd; ++k)
        word_s[k][tl] = (u16)(3072 + ((l + k) & 31));

    const uint4* __restrict__ row = (const uint4*)(nbrR + n * MAXDEG);
    int maxk = 15;

    for (int c8 = 0; c8 < (cap + 7) / 8; ++c8) {
        uint4 w = row[c8];
        int rk[8];
        rk[0] = w.x & 0xFFFF; rk[1] = w.x >> 16;
        rk[2] = w.y & 0xFFFF; rk[3] = w.y >> 16;
        rk[4] = w.z & 0xFFFF; rk[5] = w.z >> 16;
        rk[6] = w.w & 0xFFFF; rk[7] = w.w >> 16;

        int lim = cap - c8 * 8; if (lim > 8) lim = 8;
        #pragma unroll
        for (int u = 0; u < 8; ++u) {
            if (u >= lim) break;
            int v = rk[u];
            int b0 = v & 31;
            int h  = (v >> 5) & 31;
            int res0 = (b0 - l) & 31;
            int res1 = ((b0 ^ h) - l) & 31;
            int res2 = ((b0 ^ ((13 * h + 5) & 31)) - l) & 31;
            int f0 = (int)((freep >> (2 * res0)) & 3);
            int f1 = (int)((freep >> (2 * res1)) & 3);
            int f2 = (int)((freep >> (2 * res2)) & 3);
            int resw, fw, word;
            if (f0 > 0 && f0 >= f1 && f0 >= f2) {
                resw = res0; fw = f0; word = v;
            } else if (f1 > 0 && f1 >= f2) {
                resw = res1; fw = f1; word = bofsB(v);
            } else if (f2 > 0) {
                resw = res2; fw = f2; word = bofsC(v);
            } else {
                fw = 0; resw = 0; word = v;
            }
            if (fw > 0) {
                int kslot = resw + 32 * (cnt_res(pd, resw) - fw);
                freep -= 1ull << (2 * resw);
                word_s[kslot][tl] = (u16)word;
                if (kslot > maxk) maxk = kslot;
            } else {
                // bounded eviction: probe chain-head occupant of each residue
                int done = 0;
                if (cnt_res(pd, res0) > 0) {
                    int wo = word_s[res0][tl];
                    if (wo < 3072) {
                        int k2 = reloc_one(freep, pd, l, tl, v_of_word(wo), word_s);
                        if (k2 >= 0) {
                            word_s[res0][tl] = (u16)v;          // copy A matched
                            if (k2 > maxk) maxk = k2;
                            if (res0 > maxk) maxk = res0;
                            done = 1;
                        }
                    }
                }
                if (!done && cnt_res(pd, res1) > 0) {
                    int wo = word_s[res1][tl];
                    if (wo < 3072) {
                        int k2 = reloc_one(freep, pd, l, tl, v_of_word(wo), word_s);
                        if (k2 >= 0) {
                            word_s[res1][tl] = (u16)bofsB(v);   // copy B matched
                            if (k2 > maxk) maxk = k2;
                            if (res1 > maxk) maxk = res1;
                            done = 1;
                        }
                    }
                }
                if (!done && cnt_res(pd, res2) > 0) {
                    int wo = word_s[res2][tl];
                    if (wo < 3072) {
                        int k2 = reloc_one(freep, pd, l, tl, v_of_word(wo), word_s);
                        if (k2 >= 0) {
                            word_s[res2][tl] = (u16)bofsC(v);   // copy C matched
                            if (k2 > maxk) maxk = k2;
                            if (res2 > maxk) maxk = res2;
                            done = 1;
                        }
                    }
                }
                if (!done) {               // overflow: any free residue, copy A mismatched
                    for (int res = 0; res < 32; ++res) {
                        int f = (int)((freep >> (2 * res)) & 3);
                        if (f > 0) {
                            int kslot = res + 32 * (cnt_res(pd, res) - f);
                            freep -= 1ull << (2 * res);
                            word_s[kslot][tl] = (u16)v;
                            if (kslot > maxk) maxk = kslot;
                            break;
                        }
                    }
                }
            }
        }
    }

    // batched emit: one uint4 (8 byte-offsets) global store per group
    const int ng = (maxk >> 3) + 1;
    for (int g = 0; g < ng; ++g) {
        unsigned a0 = (unsigned)word_s[g * 8 + 0][tl] * 4u;
        unsigned a1 = (unsigned)word_s[g * 8 + 1][tl] * 4u;
        unsigned a2 = (unsigned)word_s[g * 8 + 2][tl] * 4u;
        unsigned a3 = (unsigned)word_s[g * 8 + 3][tl] * 4u;
        unsigned a4 = (unsigned)word_s[g * 8 + 4][tl] * 4u;
        unsigned a5 = (unsigned)word_s[g * 8 + 5][tl] * 4u;
        unsigned a6 = (unsigned)word_s[g * 8 + 6][tl] * 4u;
        unsigned a7 = (unsigned)word_s[g * 8 + 7][tl] * 4u;
        uint4 pk;
        pk.x = a0 | (a1 << 16);
        pk.y = a2 | (a3 << 16);
        pk.z = a4 | (a5 << 16);
        pk.w = a6 | (a7 << 16);
        *(uint4*)(nbr8 + (g << 13) + (r << 3)) = pk;
    }
    ngrp_r[r] = ng;
    invd_r[r] = 0.35f / ((float)dg + 1e-7f);   // OMEGA*GAMMA/(in_deg+1e-7)
}

// LDS-only barrier: order LDS ops, do NOT drain vmcnt.
#define LDS_BARRIER() asm volatile("s_waitcnt lgkmcnt(0)\n\ts_barrier" ::: "memory")

// ---------------- main simulation (R17/R19 structure, verbatim — rolled loop) ----------------
__global__ __launch_bounds__(1024) void sim_kernel(
    const float* __restrict__ x0, const float* __restrict__ t,
    const float* __restrict__ speed, const float* __restrict__ vola,
    const float* __restrict__ noise, const int* __restrict__ items,
    const u16* __restrict__ nbr8, const int* __restrict__ node_of,
    const int* __restrict__ rank_of,
    const int* __restrict__ ngrp_r, const float* __restrict__ invd_r,
    float* __restrict__ out)
{
    __shared__ float xb[2][3104];       // A + B + C copies + 32 zero sentinels
    __shared__ float4 cst[TT - 1];      // per-step {e, scale, item_as_float, -}

    const int s   = blockIdx.x;
    const int tid = threadIdx.x;

    const float sp = speed[s];
    const float vo = vola[s];

    if (tid < TT - 1) {
        float t0 = t[s * TT + tid], t1 = t[s * TT + tid + 1];
        float dt = t1 - t0;
        float e  = expf(-sp * dt);
        float sc = vo * sqrtf((1.0f - e * e) / (2.0f * sp + 1e-6f));
        int   it = items[s * TT + tid + 1];
        cst[tid] = make_float4(e, sc, __int_as_float(it), 0.0f);
    }

    const int   m     = node_of[tid];     // node this thread simulates
    const int   r_out = rank_of[tid];     // rank holding node `tid` (for out staging)
    const int   wB    = bofsB(tid);       // this thread's copy-B/C write words
    const int   wC    = bofsC(tid);

    const float x0m = x0[m];
    xb[0][tid] = x0m;
    xb[0][wB]  = x0m;
    xb[0][wC]  = x0m;
    if (tid < 32) { xb[0][3072 + tid] = 0.0f; xb[1][3072 + tid] = 0.0f; }

    float* __restrict__ outp = out + (size_t)s * TT * NN + tid;
    outp[0] = x0[tid];                    // coalesced

    const int   ng   = ngrp_r[tid];
    const float invd = invd_r[tid];
    const int   item0 = items[s * TT];
    float a_f = (m == item0) ? 1.0f : 0.0f;
    float s_f = 0.0f;

    // per-node noise register pipeline, 2 steps ahead
    const float* __restrict__ nzm = noise + (size_t)s * (TT - 1) * NN + m;
    float nzA = nzm[0];
    float nzB = nzm[NN];

    // preload ALL neighbor index groups into registers
    const uint4* __restrict__ nb = (const uint4*)nbr8 + tid;   // group stride 1024
    uint4 q0  = nb[0];
    uint4 q1  = nb[1024];
    uint4 q2  = nb[2048];
    uint4 q3  = nb[3072];
    uint4 q4  = nb[4096];
    uint4 q5  = nb[5120];
    uint4 q6  = nb[6144];
    uint4 q7  = nb[7168];
    uint4 q8  = nb[8192];
    uint4 q9  = nb[9216];
    uint4 q10 = nb[10240];
    uint4 q11 = nb[11264];

    __syncthreads();                      // one full barrier after init

    float x_own = x0m;

#define G8(V)                                                   \
    acc += *(const float*)(xc + ((V).x & 0xFFFFu));             \
    acc += *(const float*)(xc + ((V).x >> 16));                 \
    acc += *(const float*)(xc + ((V).y & 0xFFFFu));             \
    acc += *(const float*)(xc + ((V).y >> 16));                 \
    acc += *(const float*)(xc + ((V).z & 0xFFFFu));             \
    acc += *(const float*)(xc + ((V).z >> 16));                 \
    acc += *(const float*)(xc + ((V).w & 0xFFFFu));             \
    acc += *(const float*)(xc + ((V).w >> 16));

    for (int i = 0; i < TT - 1; ++i) {
        const float* __restrict__ src = xb[i & 1];
        float* __restrict__ dst       = xb[(i + 1) & 1];
        const float4 c = cst[i];

        // prefetch noise for step i+2 (latency hidden across 2 barriers)
        int ipre = (i + 2 < TT - 1) ? (i + 2) : (TT - 2);
        float nz_new = nzm[(size_t)ipre * NN];

        float xi_lin = src[r_out];        // prev value of node `tid` (permutation read)

        float acc = 0.0f;
        const char* xc = (const char*)src;
        G8(q0); G8(q1);
        if (ng > 2) { G8(q2);
        if (ng > 3) { G8(q3);
        if (ng > 4) { G8(q4);
        if (ng > 5) { G8(q5);
        if (ng > 6) { G8(q6);
        if (ng > 7) { G8(q7);
        if (ng > 8) { G8(q8);
        if (ng > 9) { G8(q9);
        if (ng > 10){ G8(q10);
        if (ng > 11){ G8(q11); } } } } } } } } } }

        float nz = nzA * c.y;
        float r  = s_f / (a_f + 1e-6f);
        float level = fmaf(acc, invd, 0.5f * r * r);
        float xn = fmaf(x_own, c.x, fmaf(1.0f - c.x, level, nz));

        dst[tid] = xn;                    // copy A: linear, conflict-free
        dst[wB]  = xn;                    // copy B: XOR-permuted, conflict-free
        dst[wC]  = xn;                    // copy C: XOR-permuted, conflict-free
        if (i) outp[(size_t)i * NN] = xi_lin;          // coalesced, 1-step delayed

        if (m == __float_as_int(c.z)) {
            a_f += 1.0f;
            s_f += (xn >= 0.0f) ? 1.0f : 0.0f;
        }
        x_own = xn;
        nzA = nzB; nzB = nz_new;
        LDS_BARRIER();                    // LDS-only: no vmcnt drain
    }
#undef G8

    outp[(size_t)(TT - 1) * NN] = xb[1][r_out];   // final state lives in buffer 1
}

extern "C" void kernel_launch(void* const* d_in, const int* in_sizes, int n_in,
                              void* d_out, int out_size, void* d_ws, size_t ws_size,
                              hipStream_t stream)
{
    const float* x0    = (const float*)d_in[0];
    const float* t     = (const float*)d_in[1];
    const float* speed = (const float*)d_in[2];
    const float* vola  = (const float*)d_in[3];
    const float* adj   = (const float*)d_in[4];
    const float* noise = (const float*)d_in[5];
    const int*   items = (const int*)d_in[6];
    float* out = (float*)d_out;

    char* ws = (char*)d_ws;
    int*   cnt_part = (int*)ws;                       // 64 KB
    int*   deg_r    = (int*)(ws + 65536);             // 4 KB (degree by rank)
    int*   rank_of  = (int*)(ws + 65536 + 4096);      // 4 KB
    int*   node_of  = (int*)(ws + 65536 + 8192);      // 4 KB
    int*   ngrp_r   = (int*)(ws + 65536 + 12288);     // 4 KB
    float* invd_r   = (float*)(ws + 65536 + 16384);   // 4 KB
    u16*   nbrR     = (u16*)(ws + 65536 + 20480);     // 192 KB (neighbor RANKS)
    u16*   nbr8     = (u16*)(ws + 65536 + 20480 + 196608); // 192 KB

    k1_count<<<256, 64, 0, stream>>>(adj, cnt_part);
    k23_rank<<<1, 1024, 0, stream>>>(cnt_part, deg_r, rank_of, node_of);
    k4_fill<<<256, 64, 0, stream>>>(adj, cnt_part, rank_of, nbrR);
    p3_sched<<<16, 64, 0, stream>>>(nbrR, deg_r, node_of, nbr8, ngrp_r, invd_r);
    sim_kernel<<<64, 1024, 0, stream>>>(x0, t, speed, vola, noise, items,
                                        nbr8, node_of, rank_of, ngrp_r, invd_r, out);
}